// Round 1
// baseline (244.568 us; speedup 1.0000x reference)
//
#include <hip/hip_runtime.h>
#include <cstdint>
#include <cmath>

#define DEV __device__ __forceinline__

typedef float v4f __attribute__((ext_vector_type(4)));
typedef short v8s __attribute__((ext_vector_type(8)));

// Problem constants
// x: [8,256,48,48] f32; weight: [256,256,3,3]; off_w: [18,256,3,3]; off_b:[18];
// mask_w: [9,256,3,3]; mask_b:[9]; out: [8,256,48,48] f32
static constexpr int HW    = 48 * 48;        // 2304
static constexpr int NPOS  = 8 * HW;         // 18432
static constexpr int KDIM  = 9 * 256;        // 2304 (k-major: K = k*256 + c)

DEV float bf2f(unsigned short u) {
  unsigned int v = ((unsigned int)u) << 16;
  float f; __builtin_memcpy(&f, &v, 4); return f;
}
DEV unsigned short f2bf(float f) {
  unsigned int u; __builtin_memcpy(&u, &f, 4);
  unsigned int r = (u + 0x7fffu + ((u >> 16) & 1u)) >> 16;
  return (unsigned short)r;
}

DEV void gload16(const void* g, void* l) {
  __builtin_amdgcn_global_load_lds(
      (const __attribute__((address_space(1))) unsigned int*)g,
      (__attribute__((address_space(3))) unsigned int*)l, 16, 0, 0);
}

// ---------------- prep: combined offset/mask weights -> Wc[c][t][o27] f32 ----
__global__ void k_wc(const float* __restrict__ off_w, const float* __restrict__ mask_w,
                     float* __restrict__ Wc) {
  int i = blockIdx.x * 256 + threadIdx.x;     // 27*2304 = 62208
  if (i >= 27 * 2304) return;
  int o = i % 27; int ct = i / 27; int t = ct % 9; int c = ct / 9;
  float v = (o < 18) ? off_w[(o * 256 + c) * 9 + t]
                     : mask_w[((o - 18) * 256 + c) * 9 + t];
  Wc[i] = v;
}

// ---------------- prep: weight OIHW f32 -> wG[co][k*256+c] bf16 --------------
__global__ void k_wg(const float* __restrict__ weight, unsigned short* __restrict__ wG) {
  __shared__ float wrow[2304];
  int co = blockIdx.x;
  const float* wsrc = weight + (size_t)co * 2304;
  for (int i = threadIdx.x; i < 2304; i += 256) wrow[i] = wsrc[i];
  __syncthreads();
  unsigned short* dst = wG + (size_t)co * 2304;
  #pragma unroll
  for (int k = 0; k < 9; k++)
    dst[k * 256 + threadIdx.x] = f2bf(wrow[threadIdx.x * 9 + k]);
}

// ---------------- prep: x NCHW f32 -> xT [b][hw][c] bf16 ---------------------
__global__ void k_xt(const float* __restrict__ x, unsigned short* __restrict__ xT) {
  __shared__ float tile[64][65];
  int bid = blockIdx.x;                 // b*144 + hwt*4 + ct
  int ct = bid & 3; int hwt = (bid >> 2) % 36; int b = bid / 144;
  int c0 = ct * 64, hw0 = hwt * 64;
  int tl = threadIdx.x & 63, tr = threadIdx.x >> 6;
  const float* xb = x + (size_t)(b * 256 + c0) * 2304 + hw0;
  #pragma unroll
  for (int r = 0; r < 16; r++) {
    int cr = tr + r * 4;
    tile[cr][tl] = xb[(size_t)cr * 2304 + tl];
  }
  __syncthreads();
  unsigned short* xo = xT + ((size_t)b * 2304 + hw0) * 256 + c0;
  #pragma unroll
  for (int r = 0; r < 16; r++) {
    int hr = tr + r * 4;
    xo[(size_t)hr * 256 + tl] = f2bf(tile[tl][hr]);
  }
}

// ---------------- offset/mask conv, split-K over 8 channel groups ------------
__global__ __launch_bounds__(256) void k_conv(const float* __restrict__ x,
                                              const float* __restrict__ Wc,
                                              float* __restrict__ partial) {
  int pos = blockIdx.x * 256 + threadIdx.x;   // 18432
  int b = pos / 2304, hw = pos % 2304;
  int h = hw / 48, w = hw % 48;
  int cg = blockIdx.y;                        // 8 groups x 32 ch
  const float* xb  = x  + (size_t)(b * 256 + cg * 32) * 2304;
  const float* wcb = Wc + (size_t)cg * 32 * 243;
  float acc[27];
  #pragma unroll
  for (int o = 0; o < 27; o++) acc[o] = 0.f;
  for (int ci = 0; ci < 32; ci++) {
    const float* xc = xb  + (size_t)ci * 2304;
    const float* wc = wcb + ci * 243;
    #pragma unroll
    for (int t = 0; t < 9; t++) {
      int dy = t / 3 - 1, dx = t % 3 - 1;
      int yy = h + dy, xx = w + dx;
      float xv = (yy >= 0 && yy < 48 && xx >= 0 && xx < 48) ? xc[yy * 48 + xx] : 0.f;
      const float* wt = wc + t * 27;          // uniform -> scalar loads
      #pragma unroll
      for (int o = 0; o < 27; o++) acc[o] = fmaf(xv, wt[o], acc[o]);
    }
  }
  float* pp = partial + ((size_t)cg * NPOS + pos) * 27;
  #pragma unroll
  for (int o = 0; o < 27; o++) pp[o] = acc[o];
}

// ---------------- finalize: reduce partials, bias, sigmoid, coords -----------
__global__ void k_fin(const float* __restrict__ partial, const float* __restrict__ off_b,
                      const float* __restrict__ mask_b, float* __restrict__ smp) {
  int pos = blockIdx.x * 256 + threadIdx.x;
  int hw = pos % 2304; int h = hw / 48, w = hw % 48;
  float s[27];
  #pragma unroll
  for (int o = 0; o < 27; o++) s[o] = 0.f;
  for (int g = 0; g < 8; g++) {
    const float* pp = partial + ((size_t)g * NPOS + pos) * 27;
    #pragma unroll
    for (int o = 0; o < 27; o++) s[o] += pp[o];
  }
  float* sp = smp + (size_t)pos * 27;         // [pos][k][{py,px,m}]
  #pragma unroll
  for (int k = 0; k < 9; k++) {
    float dy = s[2 * k]     + off_b[2 * k];
    float dx = s[2 * k + 1] + off_b[2 * k + 1];
    float mv = s[18 + k]    + mask_b[k];
    float m  = 1.f / (1.f + expf(-mv));
    sp[k * 3 + 0] = dy + (float)(k / 3) + (float)h - 1.f;
    sp[k * 3 + 1] = dx + (float)(k % 3) + (float)w - 1.f;
    sp[k * 3 + 2] = m;
  }
}

// ---------------- deformable im2col: val[n][k*256+c] bf16 --------------------
__global__ __launch_bounds__(256) void k_gather(const unsigned short* __restrict__ xT,
                                                const float* __restrict__ smp,
                                                unsigned short* __restrict__ val) {
  int task = blockIdx.x * 4 + (threadIdx.x >> 6);  // (b,hw,k), 165888 waves
  int lane = threadIdx.x & 63;
  int k = task % 9; int pos = task / 9;
  int b = pos / 2304;
  const float* sp = smp + ((size_t)pos * 9 + k) * 3;
  float py = sp[0], px = sp[1], m = sp[2];
  float y0f = floorf(py), x0f = floorf(px);
  float wy = py - y0f, wx = px - x0f;
  int y0 = (int)y0f, x0 = (int)x0f;
  bool vy0 = (y0 >= 0) && (y0 <= 47), vy1 = (y0 >= -1) && (y0 <= 46);
  bool vx0 = (x0 >= 0) && (x0 <= 47), vx1 = (x0 >= -1) && (x0 <= 46);
  int yc0 = min(max(y0, 0), 47), yc1 = min(max(y0 + 1, 0), 47);
  int xc0 = min(max(x0, 0), 47), xc1 = min(max(x0 + 1, 0), 47);
  float w00 = (1.f - wy) * (1.f - wx) * m * (float)(vy0 && vx0);
  float w01 = (1.f - wy) * wx         * m * (float)(vy0 && vx1);
  float w10 = wy         * (1.f - wx) * m * (float)(vy1 && vx0);
  float w11 = wy         * wx         * m * (float)(vy1 && vx1);
  const unsigned short* xb = xT + (size_t)b * 2304 * 256;
  int a00 = (yc0 * 48 + xc0) * 256, a01 = (yc0 * 48 + xc1) * 256;
  int a10 = (yc1 * 48 + xc0) * 256, a11 = (yc1 * 48 + xc1) * 256;
  unsigned short* vo = val + (size_t)pos * KDIM + k * 256;
  #pragma unroll
  for (int cc = 0; cc < 4; cc++) {
    int c = cc * 64 + lane;
    float f00 = bf2f(xb[a00 + c]), f01 = bf2f(xb[a01 + c]);
    float f10 = bf2f(xb[a10 + c]), f11 = bf2f(xb[a11 + c]);
    float v = w00 * f00 + w01 * f01 + w10 * f10 + w11 * f11;
    vo[c] = f2bf(v);
  }
}

// ---------------- main GEMM: C[co][n] = sum_K wG[co][K] * val[n][K] ----------
// M=256 (2 tiles of 128), N=18432 (288 tiles of 64), K=2304, BK=64
__global__ __launch_bounds__(256) void k_gemm(const unsigned short* __restrict__ wG,
                                              const unsigned short* __restrict__ val,
                                              float* __restrict__ out) {
  __shared__ unsigned short ldsA[128 * 64];   // [row co][k] 128B rows
  __shared__ unsigned short ldsB[64 * 64];    // [row n ][k]
  int bid = blockIdx.x;
  int mt = bid & 1, nt = bid >> 1;
  int co0 = mt * 128, n0 = nt * 64;
  int tid = threadIdx.x;
  int lane = tid & 63, wid = tid >> 6;
  int wm = wid >> 1, wn = wid & 1;            // 2x2 waves, wave tile 64x32
  int r = lane & 15, q = lane >> 4;

  const unsigned short* Ag = wG  + (size_t)(co0 + (tid >> 3)) * 2304 + (tid & 7) * 8;
  const unsigned short* Bg = val + (size_t)(n0  + (tid >> 3)) * 2304 + (tid & 7) * 8;
  unsigned short* la = ldsA + tid * 8;
  unsigned short* lb = ldsB + tid * 8;

  v4f acc[4][2];
  #pragma unroll
  for (int i = 0; i < 4; i++)
    #pragma unroll
    for (int j = 0; j < 2; j++) acc[i][j] = (v4f){0.f, 0.f, 0.f, 0.f};

  for (int ks = 0; ks < 36; ks++) {
    int k0 = ks * 64;
    __syncthreads();                          // all reads of prev tile done
    #pragma unroll
    for (int i = 0; i < 4; i++)               // A: 16KB = 4 rounds of 4KB
      gload16(Ag + k0 + (size_t)i * 32 * 2304, la + i * 2048);
    #pragma unroll
    for (int i = 0; i < 2; i++)               // B: 8KB = 2 rounds
      gload16(Bg + k0 + (size_t)i * 32 * 2304, lb + i * 2048);
    __syncthreads();                          // compiler drains vmcnt before barrier
    #pragma unroll
    for (int ki = 0; ki < 2; ki++) {
      int kb = ki * 32 + q * 8;
      v8s af[4], bf[2];
      #pragma unroll
      for (int fm = 0; fm < 4; fm++)
        af[fm] = *(const v8s*)&ldsA[(wm * 64 + fm * 16 + r) * 64 + kb];
      #pragma unroll
      for (int fn = 0; fn < 2; fn++)
        bf[fn] = *(const v8s*)&ldsB[(wn * 32 + fn * 16 + r) * 64 + kb];
      #pragma unroll
      for (int fm = 0; fm < 4; fm++)
        #pragma unroll
        for (int fn = 0; fn < 2; fn++)
          acc[fm][fn] = __builtin_amdgcn_mfma_f32_16x16x32_bf16(af[fm], bf[fn], acc[fm][fn], 0, 0, 0);
    }
  }

  int bimg = n0 / 2304, hw0 = n0 % 2304;      // BN=64 divides 2304: single image
  float* op = out + (size_t)bimg * (256 * 2304) + hw0;
  #pragma unroll
  for (int fm = 0; fm < 4; fm++) {
    int co = co0 + wm * 64 + fm * 16 + q * 4;
    #pragma unroll
    for (int fn = 0; fn < 2; fn++) {
      int nn = wn * 32 + fn * 16 + r;
      #pragma unroll
      for (int e = 0; e < 4; e++)
        op[(size_t)(co + e) * 2304 + nn] = acc[fm][fn][e];
    }
  }
}

extern "C" void kernel_launch(void* const* d_in, const int* in_sizes, int n_in,
                              void* d_out, int out_size, void* d_ws, size_t ws_size,
                              hipStream_t stream) {
  const float* x      = (const float*)d_in[0];
  const float* weight = (const float*)d_in[1];
  const float* off_w  = (const float*)d_in[2];
  const float* off_b  = (const float*)d_in[3];
  const float* mask_w = (const float*)d_in[4];
  const float* mask_b = (const float*)d_in[5];
  float* out = (float*)d_out;
  char* ws = (char*)d_ws;

  unsigned short* xT  = (unsigned short*)(ws);              //  9,437,184 B
  unsigned short* wG  = (unsigned short*)(ws + 9437184);    //  1,179,648 B
  float*          Wc  = (float*)(ws + 10616832);            //    248,832 B
  float*          smp = (float*)(ws + 10865664);            //  1,990,656 B
  float*          par = (float*)(ws + 12856320);            // 15,925,248 B
  unsigned short* val = (unsigned short*)(ws + 28781568);   // 84,934,656 B  (end ~108.5 MB)

  hipLaunchKernelGGL(k_wc,     dim3(243),    dim3(256), 0, stream, off_w, mask_w, Wc);
  hipLaunchKernelGGL(k_wg,     dim3(256),    dim3(256), 0, stream, weight, wG);
  hipLaunchKernelGGL(k_xt,     dim3(1152),   dim3(256), 0, stream, x, xT);
  hipLaunchKernelGGL(k_conv,   dim3(72, 8),  dim3(256), 0, stream, x, Wc, par);
  hipLaunchKernelGGL(k_fin,    dim3(72),     dim3(256), 0, stream, par, off_b, mask_b, smp);
  hipLaunchKernelGGL(k_gather, dim3(41472),  dim3(256), 0, stream, xT, smp, val);
  hipLaunchKernelGGL(k_gemm,   dim3(576),    dim3(256), 0, stream, wG, val, out);
}

// Round 2
// 160.728 us; speedup vs baseline: 1.5216x; 1.5216x over previous
//
#include <hip/hip_runtime.h>
#include <cstdint>
#include <cmath>

#define DEV __device__ __forceinline__

typedef float v4f __attribute__((ext_vector_type(4)));
typedef short v8s __attribute__((ext_vector_type(8)));

// Problem constants
// x: [8,256,48,48] f32; weight: [256,256,3,3]; off_w: [18,256,3,3]; off_b:[18];
// mask_w: [9,256,3,3]; mask_b:[9]; out: [8,256,48,48] f32
static constexpr int HW    = 48 * 48;        // 2304
static constexpr int NPOS  = 8 * HW;         // 18432
static constexpr int KDIM  = 9 * 256;        // 2304 (k-major: K = k*256 + c)
static constexpr int NGRP  = 16;             // channel groups for offset conv

DEV float bf2f(unsigned short u) {
  unsigned int v = ((unsigned int)u) << 16;
  float f; __builtin_memcpy(&f, &v, 4); return f;
}
DEV unsigned short f2bf(float f) {
  unsigned int u; __builtin_memcpy(&u, &f, 4);
  unsigned int r = (u + 0x7fffu + ((u >> 16) & 1u)) >> 16;
  return (unsigned short)r;
}

DEV void gload16(const void* g, void* l) {
  __builtin_amdgcn_global_load_lds(
      (const __attribute__((address_space(1))) unsigned int*)g,
      (__attribute__((address_space(3))) unsigned int*)l, 16, 0, 0);
}

// ---------------- prep: combined offset/mask weights -> Wc[c][t][o27] f32 ----
__global__ void k_wc(const float* __restrict__ off_w, const float* __restrict__ mask_w,
                     float* __restrict__ Wc) {
  int i = blockIdx.x * 256 + threadIdx.x;     // 27*2304 = 62208
  if (i >= 27 * 2304) return;
  int o = i % 27; int ct = i / 27; int t = ct % 9; int c = ct / 9;
  float v = (o < 18) ? off_w[(o * 256 + c) * 9 + t]
                     : mask_w[((o - 18) * 256 + c) * 9 + t];
  Wc[i] = v;
}

// ---------------- prep: weight OIHW f32 -> wG[co][k*256+c] bf16 --------------
__global__ void k_wg(const float* __restrict__ weight, unsigned short* __restrict__ wG) {
  __shared__ float wrow[2304];
  int co = blockIdx.x;
  const float* wsrc = weight + (size_t)co * 2304;
  for (int i = threadIdx.x; i < 2304; i += 256) wrow[i] = wsrc[i];
  __syncthreads();
  unsigned short* dst = wG + (size_t)co * 2304;
  #pragma unroll
  for (int k = 0; k < 9; k++)
    dst[k * 256 + threadIdx.x] = f2bf(wrow[threadIdx.x * 9 + k]);
}

// ---------------- prep: x NCHW f32 -> xT [b][hw][c] bf16 ---------------------
__global__ void k_xt(const float* __restrict__ x, unsigned short* __restrict__ xT) {
  __shared__ float tile[64][65];
  int bid = blockIdx.x;                 // b*144 + hwt*4 + ct
  int ct = bid & 3; int hwt = (bid >> 2) % 36; int b = bid / 144;
  int c0 = ct * 64, hw0 = hwt * 64;
  int tl = threadIdx.x & 63, tr = threadIdx.x >> 6;
  const float* xb = x + (size_t)(b * 256 + c0) * 2304 + hw0;
  #pragma unroll
  for (int r = 0; r < 16; r++) {
    int cr = tr + r * 4;
    tile[cr][tl] = xb[(size_t)cr * 2304 + tl];
  }
  __syncthreads();
  unsigned short* xo = xT + ((size_t)b * 2304 + hw0) * 256 + c0;
  #pragma unroll
  for (int r = 0; r < 16; r++) {
    int hr = tr + r * 4;
    xo[(size_t)hr * 256 + tl] = f2bf(tile[tl][hr]);
  }
}

// ---------------- offset/mask conv, split-K over 16 channel groups -----------
// partial layout: [g][o27][NPOS]  (pos-fastest -> coalesced stores & loads)
__global__ __launch_bounds__(256) void k_conv(const float* __restrict__ x,
                                              const float* __restrict__ Wc,
                                              float* __restrict__ partial) {
  int b = blockIdx.x / 9;                     // 9 blocks per image (2304/256)
  int hw = (blockIdx.x % 9) * 256 + threadIdx.x;
  int pos = b * 2304 + hw;
  int h = hw / 48, w = hw % 48;
  int cg = blockIdx.y;                        // 16 groups x 16 ch
  const float* xb  = x  + (size_t)(b * 256 + cg * 16) * 2304;   // scalar base
  const float* wcb = Wc + (size_t)cg * 16 * 243;                // scalar base

  int offs[9]; float vmask[9];
  #pragma unroll
  for (int t = 0; t < 9; t++) {
    int dy = t / 3 - 1, dx = t % 3 - 1;
    int yy = h + dy, xx = w + dx;
    bool v = (yy >= 0 && yy < 48 && xx >= 0 && xx < 48);
    offs[t] = v ? (yy * 48 + xx) : 0;
    vmask[t] = v ? 1.f : 0.f;
  }

  float acc[27];
  #pragma unroll
  for (int o = 0; o < 27; o++) acc[o] = 0.f;

  float xcur[9], xnxt[9];
  #pragma unroll
  for (int t = 0; t < 9; t++) xcur[t] = xb[offs[t]] * vmask[t];

  for (int ci = 0; ci < 16; ci++) {
    const float* xn = xb + (size_t)(ci + 1) * 2304;
    if (ci < 15) {
      #pragma unroll
      for (int t = 0; t < 9; t++) xnxt[t] = xn[offs[t]] * vmask[t];
    }
    const float* wc = wcb + ci * 243;         // scalar -> s_load weights
    #pragma unroll
    for (int t = 0; t < 9; t++) {
      #pragma unroll
      for (int o = 0; o < 27; o++) acc[o] = fmaf(xcur[t], wc[t * 27 + o], acc[o]);
    }
    #pragma unroll
    for (int t = 0; t < 9; t++) xcur[t] = xnxt[t];
  }

  float* pp = partial + (size_t)cg * 27 * NPOS + pos;
  #pragma unroll
  for (int o = 0; o < 27; o++) pp[(size_t)o * NPOS] = acc[o];
}

// ---------------- finalize: reduce partials, bias, sigmoid, coords -----------
// smp layout: [k][pos][{py,px,m}]
__global__ __launch_bounds__(256) void k_fin(const float* __restrict__ partial,
                                             const float* __restrict__ off_b,
                                             const float* __restrict__ mask_b,
                                             float* __restrict__ smp) {
  int k = blockIdx.x / 72;                    // 72 blocks per k (NPOS/256)
  int pos = (blockIdx.x % 72) * 256 + threadIdx.x;
  float s0 = 0.f, s1 = 0.f, s2 = 0.f;
  #pragma unroll 4
  for (int g = 0; g < NGRP; g++) {
    const float* pg = partial + (size_t)g * 27 * NPOS + pos;
    s0 += pg[(size_t)(2 * k)     * NPOS];
    s1 += pg[(size_t)(2 * k + 1) * NPOS];
    s2 += pg[(size_t)(18 + k)    * NPOS];
  }
  int hw = pos % 2304; int h = hw / 48, w = hw % 48;
  float m = 1.f / (1.f + expf(-(s2 + mask_b[k])));
  float* sp = smp + ((size_t)k * NPOS + pos) * 3;
  sp[0] = s0 + off_b[2 * k]     + (float)(k / 3) + (float)h - 1.f;
  sp[1] = s1 + off_b[2 * k + 1] + (float)(k % 3) + (float)w - 1.f;
  sp[2] = m;
}

// ---------------- deformable im2col: val[n][k*256+c] bf16 --------------------
__global__ __launch_bounds__(256) void k_gather(const unsigned short* __restrict__ xT,
                                                const float* __restrict__ smp,
                                                const float* __restrict__ /*unused*/,
                                                unsigned short* __restrict__ val) {
  int task = blockIdx.x * 4 + (threadIdx.x >> 6);  // (b,hw,k), 165888 waves
  int lane = threadIdx.x & 63;
  int k = task % 9; int pos = task / 9;
  int b = pos / 2304;
  const float* sp = smp + ((size_t)k * NPOS + pos) * 3;
  float py = sp[0], px = sp[1], m = sp[2];
  float y0f = floorf(py), x0f = floorf(px);
  float wy = py - y0f, wx = px - x0f;
  int y0 = (int)y0f, x0 = (int)x0f;
  bool vy0 = (y0 >= 0) && (y0 <= 47), vy1 = (y0 >= -1) && (y0 <= 46);
  bool vx0 = (x0 >= 0) && (x0 <= 47), vx1 = (x0 >= -1) && (x0 <= 46);
  int yc0 = min(max(y0, 0), 47), yc1 = min(max(y0 + 1, 0), 47);
  int xc0 = min(max(x0, 0), 47), xc1 = min(max(x0 + 1, 0), 47);
  float w00 = (1.f - wy) * (1.f - wx) * m * (float)(vy0 && vx0);
  float w01 = (1.f - wy) * wx         * m * (float)(vy0 && vx1);
  float w10 = wy         * (1.f - wx) * m * (float)(vy1 && vx0);
  float w11 = wy         * wx         * m * (float)(vy1 && vx1);
  const unsigned short* xb = xT + (size_t)b * 2304 * 256;
  int a00 = (yc0 * 48 + xc0) * 256, a01 = (yc0 * 48 + xc1) * 256;
  int a10 = (yc1 * 48 + xc0) * 256, a11 = (yc1 * 48 + xc1) * 256;
  unsigned short* vo = val + (size_t)pos * KDIM + k * 256;
  #pragma unroll
  for (int cc = 0; cc < 4; cc++) {
    int c = cc * 64 + lane;
    float f00 = bf2f(xb[a00 + c]), f01 = bf2f(xb[a01 + c]);
    float f10 = bf2f(xb[a10 + c]), f11 = bf2f(xb[a11 + c]);
    float v = w00 * f00 + w01 * f01 + w10 * f10 + w11 * f11;
    vo[c] = f2bf(v);
  }
}

// ---------------- main GEMM: C[co][n] = sum_K wG[co][K] * val[n][K] ----------
// M=256 (2 tiles of 128), N=18432 (288 tiles of 64), K=2304, BK=64
__global__ __launch_bounds__(256) void k_gemm(const unsigned short* __restrict__ wG,
                                              const unsigned short* __restrict__ val,
                                              float* __restrict__ out) {
  __shared__ unsigned short ldsA[128 * 64];   // [row co][k] 128B rows
  __shared__ unsigned short ldsB[64 * 64];    // [row n ][k]
  int bid = blockIdx.x;
  int mt = bid & 1, nt = bid >> 1;
  int co0 = mt * 128, n0 = nt * 64;
  int tid = threadIdx.x;
  int lane = tid & 63, wid = tid >> 6;
  int wm = wid >> 1, wn = wid & 1;            // 2x2 waves, wave tile 64x32
  int r = lane & 15, q = lane >> 4;

  const unsigned short* Ag = wG  + (size_t)(co0 + (tid >> 3)) * 2304 + (tid & 7) * 8;
  const unsigned short* Bg = val + (size_t)(n0  + (tid >> 3)) * 2304 + (tid & 7) * 8;
  unsigned short* la = ldsA + tid * 8;
  unsigned short* lb = ldsB + tid * 8;

  v4f acc[4][2];
  #pragma unroll
  for (int i = 0; i < 4; i++)
    #pragma unroll
    for (int j = 0; j < 2; j++) acc[i][j] = (v4f){0.f, 0.f, 0.f, 0.f};

  for (int ks = 0; ks < 36; ks++) {
    int k0 = ks * 64;
    __syncthreads();                          // all reads of prev tile done
    #pragma unroll
    for (int i = 0; i < 4; i++)               // A: 16KB = 4 rounds of 4KB
      gload16(Ag + k0 + (size_t)i * 32 * 2304, la + i * 2048);
    #pragma unroll
    for (int i = 0; i < 2; i++)               // B: 8KB = 2 rounds
      gload16(Bg + k0 + (size_t)i * 32 * 2304, lb + i * 2048);
    __syncthreads();                          // compiler drains vmcnt before barrier
    #pragma unroll
    for (int ki = 0; ki < 2; ki++) {
      int kb = ki * 32 + q * 8;
      v8s af[4], bf[2];
      #pragma unroll
      for (int fm = 0; fm < 4; fm++)
        af[fm] = *(const v8s*)&ldsA[(wm * 64 + fm * 16 + r) * 64 + kb];
      #pragma unroll
      for (int fn = 0; fn < 2; fn++)
        bf[fn] = *(const v8s*)&ldsB[(wn * 32 + fn * 16 + r) * 64 + kb];
      #pragma unroll
      for (int fm = 0; fm < 4; fm++)
        #pragma unroll
        for (int fn = 0; fn < 2; fn++)
          acc[fm][fn] = __builtin_amdgcn_mfma_f32_16x16x32_bf16(af[fm], bf[fn], acc[fm][fn], 0, 0, 0);
    }
  }

  int bimg = n0 / 2304, hw0 = n0 % 2304;      // BN=64 divides 2304: single image
  float* op = out + (size_t)bimg * (256 * 2304) + hw0;
  #pragma unroll
  for (int fm = 0; fm < 4; fm++) {
    int co = co0 + wm * 64 + fm * 16 + q * 4;
    #pragma unroll
    for (int fn = 0; fn < 2; fn++) {
      int nn = wn * 32 + fn * 16 + r;
      #pragma unroll
      for (int e = 0; e < 4; e++)
        op[(size_t)(co + e) * 2304 + nn] = acc[fm][fn][e];
    }
  }
}

extern "C" void kernel_launch(void* const* d_in, const int* in_sizes, int n_in,
                              void* d_out, int out_size, void* d_ws, size_t ws_size,
                              hipStream_t stream) {
  const float* x      = (const float*)d_in[0];
  const float* weight = (const float*)d_in[1];
  const float* off_w  = (const float*)d_in[2];
  const float* off_b  = (const float*)d_in[3];
  const float* mask_w = (const float*)d_in[4];
  const float* mask_b = (const float*)d_in[5];
  float* out = (float*)d_out;
  char* ws = (char*)d_ws;

  unsigned short* xT  = (unsigned short*)(ws);              //  9,437,184 B
  unsigned short* wG  = (unsigned short*)(ws + 9437184);    //  1,179,648 B -> 10,616,832
  float*          Wc  = (float*)(ws + 10616832);            //    248,832 B -> 10,865,664
  float*          smp = (float*)(ws + 10865664);            //  1,990,656 B -> 12,856,320
  float*          par = (float*)(ws + 12856320);            // 31,850,496 B -> 44,706,816
  unsigned short* val = (unsigned short*)(ws + 12856320);   // overlaps par (dead after k_fin)
                                                            // 84,934,656 B -> 97,790,976

  hipLaunchKernelGGL(k_wc,     dim3(243),       dim3(256), 0, stream, off_w, mask_w, Wc);
  hipLaunchKernelGGL(k_wg,     dim3(256),       dim3(256), 0, stream, weight, wG);
  hipLaunchKernelGGL(k_xt,     dim3(1152),      dim3(256), 0, stream, x, xT);
  hipLaunchKernelGGL(k_conv,   dim3(72, NGRP),  dim3(256), 0, stream, x, Wc, par);
  hipLaunchKernelGGL(k_fin,    dim3(648),       dim3(256), 0, stream, par, off_b, mask_b, smp);
  hipLaunchKernelGGL(k_gather, dim3(41472),     dim3(256), 0, stream, xT, smp, (const float*)nullptr, val);
  hipLaunchKernelGGL(k_gemm,   dim3(576),       dim3(256), 0, stream, wG, val, out);
}

// Round 3
// 117.151 us; speedup vs baseline: 2.0876x; 1.3720x over previous
//
#include <hip/hip_runtime.h>
#include <cstdint>
#include <cmath>

#define DEV __device__ __forceinline__

typedef float v4f __attribute__((ext_vector_type(4)));
typedef short v8s __attribute__((ext_vector_type(8)));

// Problem constants
// x: [8,256,48,48] f32; weight: [256,256,3,3]; off_w: [18,256,3,3]; off_b:[18];
// mask_w: [9,256,3,3]; mask_b:[9]; out: [8,256,48,48] f32
static constexpr int HW    = 48 * 48;        // 2304
static constexpr int NPOS  = 8 * HW;         // 18432
static constexpr int KDIM  = 9 * 256;        // 2304 (k-major: K = k*256 + c)

DEV float bf2f(unsigned short u) {
  unsigned int v = ((unsigned int)u) << 16;
  float f; __builtin_memcpy(&f, &v, 4); return f;
}
DEV unsigned short f2bf(float f) {
  unsigned int u; __builtin_memcpy(&u, &f, 4);
  unsigned int r = (u + 0x7fffu + ((u >> 16) & 1u)) >> 16;
  return (unsigned short)r;
}

DEV void gload16(const void* g, void* l) {
  __builtin_amdgcn_global_load_lds(
      (const __attribute__((address_space(1))) unsigned int*)g,
      (__attribute__((address_space(3))) unsigned int*)l, 16, 0, 0);
}

// ---- prep: offset/mask weights -> Wc2[32][k=t*256+c] bf16 (rows 27..31 = 0);
//      also zero the 512B zero-page used for OOB im2col rows.
__global__ void k_wc(const float* __restrict__ off_w, const float* __restrict__ mask_w,
                     unsigned short* __restrict__ Wc2, unsigned short* __restrict__ zp) {
  int i = blockIdx.x * 256 + threadIdx.x;     // 32*2304 = 73728 (288 blocks)
  if (i < 256) zp[i] = 0;
  int o = i / 2304, col = i % 2304;
  int t = col >> 8, c = col & 255;
  float v = 0.f;
  if (o < 18)      v = off_w[(o * 256 + c) * 9 + t];
  else if (o < 27) v = mask_w[((o - 18) * 256 + c) * 9 + t];
  Wc2[i] = f2bf(v);
}

// ---------------- prep: weight OIHW f32 -> wG[co][k*256+c] bf16 --------------
__global__ void k_wg(const float* __restrict__ weight, unsigned short* __restrict__ wG) {
  __shared__ float wrow[2304];
  int co = blockIdx.x;
  const float* wsrc = weight + (size_t)co * 2304;
  for (int i = threadIdx.x; i < 2304; i += 256) wrow[i] = wsrc[i];
  __syncthreads();
  unsigned short* dst = wG + (size_t)co * 2304;
  #pragma unroll
  for (int k = 0; k < 9; k++)
    dst[k * 256 + threadIdx.x] = f2bf(wrow[threadIdx.x * 9 + k]);
}

// ---------------- prep: x NCHW f32 -> xT [b][hw][c] bf16 ---------------------
__global__ void k_xt(const float* __restrict__ x, unsigned short* __restrict__ xT) {
  __shared__ float tile[64][65];
  int bid = blockIdx.x;                 // b*144 + hwt*4 + ct
  int ct = bid & 3; int hwt = (bid >> 2) % 36; int b = bid / 144;
  int c0 = ct * 64, hw0 = hwt * 64;
  int tl = threadIdx.x & 63, tr = threadIdx.x >> 6;
  const float* xb = x + (size_t)(b * 256 + c0) * 2304 + hw0;
  #pragma unroll
  for (int r = 0; r < 16; r++) {
    int cr = tr + r * 4;
    tile[cr][tl] = xb[(size_t)cr * 2304 + tl];
  }
  __syncthreads();
  unsigned short* xo = xT + ((size_t)b * 2304 + hw0) * 256 + c0;
  #pragma unroll
  for (int r = 0; r < 16; r++) {
    int hr = tr + r * 4;
    xo[(size_t)hr * 256 + tl] = f2bf(tile[tl][hr]);
  }
}

// ---------------- offset/mask conv as MFMA GEMM ------------------------------
// S[32][NPOS] = Wc2[32][2304] * im2col(xT)[2304][NPOS], split-K by tap triple.
// grid (288, 3): BN=64, per chunk K=768 (3 taps x 256 ch), BK=64.
// parS layout: [kc][32][NPOS] fp32.
__global__ __launch_bounds__(256) void k_cg(const unsigned short* __restrict__ Wc2,
                                            const unsigned short* __restrict__ xT,
                                            const unsigned short* __restrict__ zp,
                                            float* __restrict__ parS) {
  __shared__ unsigned short ldsA[32 * 64];
  __shared__ unsigned short ldsB[64 * 64];
  int nt = blockIdx.x, kc = blockIdx.y;
  int n0 = nt * 64;
  int b = n0 / 2304, hw0 = n0 % 2304;         // BN=64 divides 2304: one image
  int tid = threadIdx.x, lane = tid & 63, wid = tid >> 6;
  int r = lane & 15, q = lane >> 4;
  int row0 = tid >> 3;                        // staging row (0..31)
  int sslot = (tid & 7) ^ (row0 & 7);         // pre-swizzled 16B slot

  int hwA = hw0 + row0,      hA = hwA / 48, wA = hwA % 48;   // B round 0 row
  int hwB = hw0 + row0 + 32, hB = hwB / 48, wB = hwB % 48;   // B round 1 row

  v4f acc0 = (v4f){0.f, 0.f, 0.f, 0.f};
  v4f acc1 = (v4f){0.f, 0.f, 0.f, 0.f};

  #pragma unroll
  for (int tt = 0; tt < 3; tt++) {
    int t = kc * 3 + tt;
    int dy = kc - 1, dx = tt - 1;
    int yA = hA + dy, xA = wA + dx;
    int yB = hB + dy, xB = wB + dx;
    bool vA = ((unsigned)yA < 48u) && ((unsigned)xA < 48u);
    bool vB = ((unsigned)yB < 48u) && ((unsigned)xB < 48u);
    const unsigned short* baseA2 = Wc2 + (size_t)row0 * 2304 + t * 256 + sslot * 8;
    const unsigned short* base0 = vA ? xT + ((size_t)(b * 2304 + yA * 48 + xA) * 256 + sslot * 8)
                                     : zp + sslot * 8;
    const unsigned short* base1 = vB ? xT + ((size_t)(b * 2304 + yB * 48 + xB) * 256 + sslot * 8)
                                     : zp + sslot * 8;
    #pragma unroll
    for (int cq = 0; cq < 4; cq++) {
      int c0s = cq * 64;
      __syncthreads();                        // prev tile reads done
      gload16(baseA2 + c0s, ldsA + tid * 8);
      gload16(base0  + c0s, ldsB + tid * 8);
      gload16(base1  + c0s, ldsB + 2048 + tid * 8);
      __syncthreads();                        // drain vmcnt + barrier
      #pragma unroll
      for (int ki = 0; ki < 2; ki++) {
        int sl = ((ki * 4 + q) ^ (r & 7)) * 8;
        v8s a0 = *(const v8s*)&ldsA[r * 64 + sl];
        v8s a1 = *(const v8s*)&ldsA[(16 + r) * 64 + sl];
        v8s bb = *(const v8s*)&ldsB[(wid * 16 + r) * 64 + sl];
        acc0 = __builtin_amdgcn_mfma_f32_16x16x32_bf16(a0, bb, acc0, 0, 0, 0);
        acc1 = __builtin_amdgcn_mfma_f32_16x16x32_bf16(a1, bb, acc1, 0, 0, 0);
      }
    }
  }

  float* pp = parS + (size_t)kc * 32 * NPOS + n0;
  #pragma unroll
  for (int e = 0; e < 4; e++) {
    pp[(size_t)(q * 4 + e) * NPOS      + wid * 16 + r] = acc0[e];
    pp[(size_t)(16 + q * 4 + e) * NPOS + wid * 16 + r] = acc1[e];
  }
}

// ---------------- finalize: reduce 3 chunks, bias, sigmoid, coords -----------
// smp layout: [k][pos][{py,px,m}]
__global__ __launch_bounds__(256) void k_fin(const float* __restrict__ parS,
                                             const float* __restrict__ off_b,
                                             const float* __restrict__ mask_b,
                                             float* __restrict__ smp) {
  int k = blockIdx.x / 72;                    // 72 blocks per k (NPOS/256)
  int pos = (blockIdx.x % 72) * 256 + threadIdx.x;
  float s0 = 0.f, s1 = 0.f, s2 = 0.f;
  #pragma unroll
  for (int g = 0; g < 3; g++) {
    const float* pg = parS + (size_t)g * 32 * NPOS + pos;
    s0 += pg[(size_t)(2 * k)     * NPOS];
    s1 += pg[(size_t)(2 * k + 1) * NPOS];
    s2 += pg[(size_t)(18 + k)    * NPOS];
  }
  int hw = pos % 2304; int h = hw / 48, w = hw % 48;
  float m = 1.f / (1.f + expf(-(s2 + mask_b[k])));
  float* sp = smp + ((size_t)k * NPOS + pos) * 3;
  sp[0] = s0 + off_b[2 * k]     + (float)(k / 3) + (float)h - 1.f;
  sp[1] = s1 + off_b[2 * k + 1] + (float)(k % 3) + (float)w - 1.f;
  sp[2] = m;
}

// ---------------- deformable im2col: val[n][k*256+c] bf16 --------------------
__global__ __launch_bounds__(256) void k_gather(const unsigned short* __restrict__ xT,
                                                const float* __restrict__ smp,
                                                unsigned short* __restrict__ val) {
  int task = blockIdx.x * 4 + (threadIdx.x >> 6);  // (b,hw,k), 165888 waves
  int lane = threadIdx.x & 63;
  int k = task % 9; int pos = task / 9;
  int b = pos / 2304;
  const float* sp = smp + ((size_t)k * NPOS + pos) * 3;
  float py = sp[0], px = sp[1], m = sp[2];
  float y0f = floorf(py), x0f = floorf(px);
  float wy = py - y0f, wx = px - x0f;
  int y0 = (int)y0f, x0 = (int)x0f;
  bool vy0 = (y0 >= 0) && (y0 <= 47), vy1 = (y0 >= -1) && (y0 <= 46);
  bool vx0 = (x0 >= 0) && (x0 <= 47), vx1 = (x0 >= -1) && (x0 <= 46);
  int yc0 = min(max(y0, 0), 47), yc1 = min(max(y0 + 1, 0), 47);
  int xc0 = min(max(x0, 0), 47), xc1 = min(max(x0 + 1, 0), 47);
  float w00 = (1.f - wy) * (1.f - wx) * m * (float)(vy0 && vx0);
  float w01 = (1.f - wy) * wx         * m * (float)(vy0 && vx1);
  float w10 = wy         * (1.f - wx) * m * (float)(vy1 && vx0);
  float w11 = wy         * wx         * m * (float)(vy1 && vx1);
  const unsigned short* xb = xT + (size_t)b * 2304 * 256;
  int a00 = (yc0 * 48 + xc0) * 256, a01 = (yc0 * 48 + xc1) * 256;
  int a10 = (yc1 * 48 + xc0) * 256, a11 = (yc1 * 48 + xc1) * 256;
  unsigned short* vo = val + (size_t)pos * KDIM + k * 256;
  #pragma unroll
  for (int cc = 0; cc < 4; cc++) {
    int c = cc * 64 + lane;
    float f00 = bf2f(xb[a00 + c]), f01 = bf2f(xb[a01 + c]);
    float f10 = bf2f(xb[a10 + c]), f11 = bf2f(xb[a11 + c]);
    float v = w00 * f00 + w01 * f01 + w10 * f10 + w11 * f11;
    vo[c] = f2bf(v);
  }
}

// ---------------- main GEMM: C[co][n] = sum_K wG[co][K] * val[n][K] ----------
// M=256 (2 tiles of 128), N=18432 (288 tiles of 64), K=2304, BK=64
__global__ __launch_bounds__(256) void k_gemm(const unsigned short* __restrict__ wG,
                                              const unsigned short* __restrict__ val,
                                              float* __restrict__ out) {
  __shared__ unsigned short ldsA[128 * 64];   // [row co][k] 128B rows
  __shared__ unsigned short ldsB[64 * 64];    // [row n ][k]
  int bid = blockIdx.x;
  int mt = bid & 1, nt = bid >> 1;
  int co0 = mt * 128, n0 = nt * 64;
  int tid = threadIdx.x;
  int lane = tid & 63, wid = tid >> 6;
  int wm = wid >> 1, wn = wid & 1;            // 2x2 waves, wave tile 64x32
  int r = lane & 15, q = lane >> 4;

  const unsigned short* Ag = wG  + (size_t)(co0 + (tid >> 3)) * 2304 + (tid & 7) * 8;
  const unsigned short* Bg = val + (size_t)(n0  + (tid >> 3)) * 2304 + (tid & 7) * 8;
  unsigned short* la = ldsA + tid * 8;
  unsigned short* lb = ldsB + tid * 8;

  v4f acc[4][2];
  #pragma unroll
  for (int i = 0; i < 4; i++)
    #pragma unroll
    for (int j = 0; j < 2; j++) acc[i][j] = (v4f){0.f, 0.f, 0.f, 0.f};

  for (int ks = 0; ks < 36; ks++) {
    int k0 = ks * 64;
    __syncthreads();                          // all reads of prev tile done
    #pragma unroll
    for (int i = 0; i < 4; i++)               // A: 16KB = 4 rounds of 4KB
      gload16(Ag + k0 + (size_t)i * 32 * 2304, la + i * 2048);
    #pragma unroll
    for (int i = 0; i < 2; i++)               // B: 8KB = 2 rounds
      gload16(Bg + k0 + (size_t)i * 32 * 2304, lb + i * 2048);
    __syncthreads();                          // compiler drains vmcnt before barrier
    #pragma unroll
    for (int ki = 0; ki < 2; ki++) {
      int kb = ki * 32 + q * 8;
      v8s af[4], bf[2];
      #pragma unroll
      for (int fm = 0; fm < 4; fm++)
        af[fm] = *(const v8s*)&ldsA[(wm * 64 + fm * 16 + r) * 64 + kb];
      #pragma unroll
      for (int fn = 0; fn < 2; fn++)
        bf[fn] = *(const v8s*)&ldsB[(wn * 32 + fn * 16 + r) * 64 + kb];
      #pragma unroll
      for (int fm = 0; fm < 4; fm++)
        #pragma unroll
        for (int fn = 0; fn < 2; fn++)
          acc[fm][fn] = __builtin_amdgcn_mfma_f32_16x16x32_bf16(af[fm], bf[fn], acc[fm][fn], 0, 0, 0);
    }
  }

  int bimg = n0 / 2304, hw0 = n0 % 2304;      // BN=64 divides 2304: single image
  float* op = out + (size_t)bimg * (256 * 2304) + hw0;
  #pragma unroll
  for (int fm = 0; fm < 4; fm++) {
    int co = co0 + wm * 64 + fm * 16 + q * 4;
    #pragma unroll
    for (int fn = 0; fn < 2; fn++) {
      int nn = wn * 32 + fn * 16 + r;
      #pragma unroll
      for (int e = 0; e < 4; e++)
        op[(size_t)(co + e) * 2304 + nn] = acc[fm][fn][e];
    }
  }
}

extern "C" void kernel_launch(void* const* d_in, const int* in_sizes, int n_in,
                              void* d_out, int out_size, void* d_ws, size_t ws_size,
                              hipStream_t stream) {
  const float* x      = (const float*)d_in[0];
  const float* weight = (const float*)d_in[1];
  const float* off_w  = (const float*)d_in[2];
  const float* off_b  = (const float*)d_in[3];
  const float* mask_w = (const float*)d_in[4];
  const float* mask_b = (const float*)d_in[5];
  float* out = (float*)d_out;
  char* ws = (char*)d_ws;

  unsigned short* xT   = (unsigned short*)(ws);             //  9,437,184 B -> 9,437,184
  unsigned short* wG   = (unsigned short*)(ws + 9437184);   //  1,179,648 B -> 10,616,832
  unsigned short* Wc2  = (unsigned short*)(ws + 10616832);  //    147,456 B -> 10,764,288
  unsigned short* zp   = (unsigned short*)(ws + 10764288);  //        512 B -> 10,764,800
  float*          smp  = (float*)(ws + 10764800);           //  1,990,656 B -> 12,755,456
  float*          parS = (float*)(ws + 12755456);           //  7,077,888 B -> 19,833,344
  unsigned short* val  = (unsigned short*)(ws + 12755456);  // overlaps parS (dead after k_fin)
                                                            // 84,934,656 B -> 97,690,112

  hipLaunchKernelGGL(k_wc,     dim3(288),      dim3(256), 0, stream, off_w, mask_w, Wc2, zp);
  hipLaunchKernelGGL(k_wg,     dim3(256),      dim3(256), 0, stream, weight, wG);
  hipLaunchKernelGGL(k_xt,     dim3(1152),     dim3(256), 0, stream, x, xT);
  hipLaunchKernelGGL(k_cg,     dim3(288, 3),   dim3(256), 0, stream, Wc2, xT, zp, parS);
  hipLaunchKernelGGL(k_fin,    dim3(648),      dim3(256), 0, stream, parS, off_b, mask_b, smp);
  hipLaunchKernelGGL(k_gather, dim3(41472),    dim3(256), 0, stream, xT, smp, val);
  hipLaunchKernelGGL(k_gemm,   dim3(576),      dim3(256), 0, stream, wG, val, out);
}

// Round 4
// 115.420 us; speedup vs baseline: 2.1189x; 1.0150x over previous
//
#include <hip/hip_runtime.h>
#include <cstdint>
#include <cmath>

#define DEV __device__ __forceinline__

typedef float v4f __attribute__((ext_vector_type(4)));
typedef short v8s __attribute__((ext_vector_type(8)));

// Problem constants
// x: [8,256,48,48] f32; weight: [256,256,3,3]; off_w: [18,256,3,3]; off_b:[18];
// mask_w: [9,256,3,3]; mask_b:[9]; out: [8,256,48,48] f32
static constexpr int HW    = 48 * 48;        // 2304
static constexpr int NPOS  = 8 * HW;         // 18432

DEV float bf2f(unsigned short u) {
  unsigned int v = ((unsigned int)u) << 16;
  float f; __builtin_memcpy(&f, &v, 4); return f;
}
DEV unsigned short f2bf(float f) {
  unsigned int u; __builtin_memcpy(&u, &f, 4);
  unsigned int r = (u + 0x7fffu + ((u >> 16) & 1u)) >> 16;
  return (unsigned short)r;
}

DEV void gload16(const void* g, void* l) {
  __builtin_amdgcn_global_load_lds(
      (const __attribute__((address_space(1))) unsigned int*)g,
      (__attribute__((address_space(3))) unsigned int*)l, 16, 0, 0);
}

// ---- prep: offset/mask weights -> Wc2[32][k=t*256+c] bf16 (rows 27..31 = 0);
//      also zero the 512B zero-page used for OOB im2col rows.
__global__ void k_wc(const float* __restrict__ off_w, const float* __restrict__ mask_w,
                     unsigned short* __restrict__ Wc2, unsigned short* __restrict__ zp) {
  int i = blockIdx.x * 256 + threadIdx.x;     // 32*2304 = 73728 (288 blocks)
  if (i < 256) zp[i] = 0;
  int o = i / 2304, col = i % 2304;
  int t = col >> 8, c = col & 255;
  float v = 0.f;
  if (o < 18)      v = off_w[(o * 256 + c) * 9 + t];
  else if (o < 27) v = mask_w[((o - 18) * 256 + c) * 9 + t];
  Wc2[i] = f2bf(v);
}

// ---------------- prep: weight OIHW f32 -> wG[co][k*256+c] bf16 --------------
__global__ void k_wg(const float* __restrict__ weight, unsigned short* __restrict__ wG) {
  __shared__ float wrow[2304];
  int co = blockIdx.x;
  const float* wsrc = weight + (size_t)co * 2304;
  for (int i = threadIdx.x; i < 2304; i += 256) wrow[i] = wsrc[i];
  __syncthreads();
  unsigned short* dst = wG + (size_t)co * 2304;
  #pragma unroll
  for (int k = 0; k < 9; k++)
    dst[k * 256 + threadIdx.x] = f2bf(wrow[threadIdx.x * 9 + k]);
}

// ---------------- prep: x NCHW f32 -> xT [b][hw][c] bf16 ---------------------
__global__ void k_xt(const float* __restrict__ x, unsigned short* __restrict__ xT) {
  __shared__ float tile[64][65];
  int bid = blockIdx.x;                 // b*144 + hwt*4 + ct
  int ct = bid & 3; int hwt = (bid >> 2) % 36; int b = bid / 144;
  int c0 = ct * 64, hw0 = hwt * 64;
  int tl = threadIdx.x & 63, tr = threadIdx.x >> 6;
  const float* xb = x + (size_t)(b * 256 + c0) * 2304 + hw0;
  #pragma unroll
  for (int r = 0; r < 16; r++) {
    int cr = tr + r * 4;
    tile[cr][tl] = xb[(size_t)cr * 2304 + tl];
  }
  __syncthreads();
  unsigned short* xo = xT + ((size_t)b * 2304 + hw0) * 256 + c0;
  #pragma unroll
  for (int r = 0; r < 16; r++) {
    int hr = tr + r * 4;
    xo[(size_t)hr * 256 + tl] = f2bf(tile[tl][hr]);
  }
}

// ---------------- offset/mask conv as MFMA GEMM ------------------------------
// S[32][NPOS] = Wc2[32][2304] * im2col(xT)[2304][NPOS], split-K by tap triple.
// grid (288, 3): BN=64, per chunk K=768 (3 taps x 256 ch), BK=64.
// parS layout: [kc][32][NPOS] fp32.
__global__ __launch_bounds__(256) void k_cg(const unsigned short* __restrict__ Wc2,
                                            const unsigned short* __restrict__ xT,
                                            const unsigned short* __restrict__ zp,
                                            float* __restrict__ parS) {
  __shared__ unsigned short ldsA[32 * 64];
  __shared__ unsigned short ldsB[64 * 64];
  int nt = blockIdx.x, kc = blockIdx.y;
  int n0 = nt * 64;
  int b = n0 / 2304, hw0 = n0 % 2304;         // BN=64 divides 2304: one image
  int tid = threadIdx.x, lane = tid & 63, wid = tid >> 6;
  int r = lane & 15, q = lane >> 4;
  int row0 = tid >> 3;                        // staging row (0..31)
  int sslot = (tid & 7) ^ (row0 & 7);         // pre-swizzled 16B slot

  int hwA = hw0 + row0,      hA = hwA / 48, wA = hwA % 48;   // B round 0 row
  int hwB = hw0 + row0 + 32, hB = hwB / 48, wB = hwB % 48;   // B round 1 row

  v4f acc0 = (v4f){0.f, 0.f, 0.f, 0.f};
  v4f acc1 = (v4f){0.f, 0.f, 0.f, 0.f};

  #pragma unroll
  for (int tt = 0; tt < 3; tt++) {
    int t = kc * 3 + tt;
    int dy = kc - 1, dx = tt - 1;
    int yA = hA + dy, xA = wA + dx;
    int yB = hB + dy, xB = wB + dx;
    bool vA = ((unsigned)yA < 48u) && ((unsigned)xA < 48u);
    bool vB = ((unsigned)yB < 48u) && ((unsigned)xB < 48u);
    const unsigned short* baseA2 = Wc2 + (size_t)row0 * 2304 + t * 256 + sslot * 8;
    const unsigned short* base0 = vA ? xT + ((size_t)(b * 2304 + yA * 48 + xA) * 256 + sslot * 8)
                                     : zp + sslot * 8;
    const unsigned short* base1 = vB ? xT + ((size_t)(b * 2304 + yB * 48 + xB) * 256 + sslot * 8)
                                     : zp + sslot * 8;
    #pragma unroll
    for (int cq = 0; cq < 4; cq++) {
      int c0s = cq * 64;
      __syncthreads();                        // prev tile reads done
      gload16(baseA2 + c0s, ldsA + tid * 8);
      gload16(base0  + c0s, ldsB + tid * 8);
      gload16(base1  + c0s, ldsB + 2048 + tid * 8);
      __syncthreads();                        // drain vmcnt + barrier
      #pragma unroll
      for (int ki = 0; ki < 2; ki++) {
        int sl = ((ki * 4 + q) ^ (r & 7)) * 8;
        v8s a0 = *(const v8s*)&ldsA[r * 64 + sl];
        v8s a1 = *(const v8s*)&ldsA[(16 + r) * 64 + sl];
        v8s bb = *(const v8s*)&ldsB[(wid * 16 + r) * 64 + sl];
        acc0 = __builtin_amdgcn_mfma_f32_16x16x32_bf16(a0, bb, acc0, 0, 0, 0);
        acc1 = __builtin_amdgcn_mfma_f32_16x16x32_bf16(a1, bb, acc1, 0, 0, 0);
      }
    }
  }

  float* pp = parS + (size_t)kc * 32 * NPOS + n0;
  #pragma unroll
  for (int e = 0; e < 4; e++) {
    pp[(size_t)(q * 4 + e) * NPOS      + wid * 16 + r] = acc0[e];
    pp[(size_t)(16 + q * 4 + e) * NPOS + wid * 16 + r] = acc1[e];
  }
}

// ---------------- finalize: reduce 3 chunks, bias, sigmoid, coords -----------
// smp layout: [k][pos][{py,px,m}]
__global__ __launch_bounds__(256) void k_fin(const float* __restrict__ parS,
                                             const float* __restrict__ off_b,
                                             const float* __restrict__ mask_b,
                                             float* __restrict__ smp) {
  int k = blockIdx.x / 72;                    // 72 blocks per k (NPOS/256)
  int pos = (blockIdx.x % 72) * 256 + threadIdx.x;
  float s0 = 0.f, s1 = 0.f, s2 = 0.f;
  #pragma unroll
  for (int g = 0; g < 3; g++) {
    const float* pg = parS + (size_t)g * 32 * NPOS + pos;
    s0 += pg[(size_t)(2 * k)     * NPOS];
    s1 += pg[(size_t)(2 * k + 1) * NPOS];
    s2 += pg[(size_t)(18 + k)    * NPOS];
  }
  int hw = pos % 2304; int h = hw / 48, w = hw % 48;
  float m = 1.f / (1.f + expf(-(s2 + mask_b[k])));
  float* sp = smp + ((size_t)k * NPOS + pos) * 3;
  sp[0] = s0 + off_b[2 * k]     + (float)(k / 3) + (float)h - 1.f;
  sp[1] = s1 + off_b[2 * k + 1] + (float)(k % 3) + (float)w - 1.f;
  sp[2] = m;
}

// ---------------- zero the output (required: fused GEMM accumulates) ---------
__global__ __launch_bounds__(256) void k_zero(float* __restrict__ out) {
  int i = blockIdx.x * 256 + threadIdx.x;     // 1179648 float4 = 4608 blocks
  ((v4f*)out)[i] = (v4f){0.f, 0.f, 0.f, 0.f};
}

// ---------------- fused deformable-gather + GEMM -----------------------------
// C[co][n] += sum_{K-half} wG[co][K] * gather(xT,smp)[K][n]
// BM=256 (full M), BN=64, BK=64. Split-K 2-way by channel-half (cq pairs).
// 576 blocks x 512 threads; XCD-swizzled so each XCD sees 2 images + wG half.
__global__ __launch_bounds__(512, 4) void k_fg(const unsigned short* __restrict__ wG,
                                               const unsigned short* __restrict__ xT,
                                               const float* __restrict__ smp,
                                               float* __restrict__ out) {
  __shared__ unsigned short ldsA[256 * 64];   // 32 KB, [co][k] swizzled slots
  __shared__ unsigned short ldsB[64 * 64];    //  8 KB, [n][k]  swizzled slots
  int raw = blockIdx.x;                       // 576 = 288 nt x 2 kc
  int vbid = (raw & 7) * 72 + (raw >> 3);     // XCD-contiguous chunks of 72
  int kc = vbid / 288, nt = vbid % 288;
  int n0 = nt * 64;
  int b = n0 / 2304, hw0 = n0 % 2304;         // 64 | 2304: single image
  int tid = threadIdx.x, lane = tid & 63, wid = tid >> 6;
  int wm = wid & 3, wn = wid >> 2;            // 4 m-waves x 2 n-waves
  int r = lane & 15, q = lane >> 4;
  int p = tid >> 3, j = tid & 7;              // gather: 8 threads per position
  int hw = hw0 + p, h = hw / 48, w = hw % 48;
  int pos = b * 2304 + hw;
  const unsigned short* xb = xT + (size_t)b * 2304 * 256;
  int aslot = j ^ (p & 7);                    // pre-swizzled A source slot

  v4f acc[4][2];
  #pragma unroll
  for (int i = 0; i < 4; i++)
    #pragma unroll
    for (int jj = 0; jj < 2; jj++) acc[i][jj] = (v4f){0.f, 0.f, 0.f, 0.f};

  #pragma unroll
  for (int cql = 0; cql < 2; cql++) {
    int c0 = (kc * 2 + cql) * 64;             // channel quarter base
    for (int t = 0; t < 9; t++) {             // tap-inner: corner rows reuse in L1
      // ---- per-position bilinear setup (8 threads redundant per position)
      const float* sp = smp + ((size_t)t * NPOS + pos) * 3;
      float py = sp[0], px = sp[1], m = sp[2];
      float y0f = floorf(py), x0f = floorf(px);
      float wy = py - y0f, wx = px - x0f;
      int y0 = (int)y0f, x0 = (int)x0f;
      bool vy0 = (y0 >= 0) && (y0 <= 47), vy1 = (y0 >= -1) && (y0 <= 46);
      bool vx0 = (x0 >= 0) && (x0 <= 47), vx1 = (x0 >= -1) && (x0 <= 46);
      int yc0 = min(max(y0, 0), 47), yc1 = min(max(y0 + 1, 0), 47);
      int xc0 = min(max(x0, 0), 47), xc1 = min(max(x0 + 1, 0), 47);
      float w00 = (1.f - wy) * (1.f - wx) * m * (float)(vy0 && vx0);
      float w01 = (1.f - wy) * wx         * m * (float)(vy0 && vx1);
      float w10 = wy         * (1.f - wx) * m * (float)(vy1 && vx0);
      float w11 = wy         * wx         * m * (float)(vy1 && vx1);
      int cb = c0 + j * 8;
      // issue corner loads early (latency hides under barrier + A staging)
      v8s c00v = *(const v8s*)&xb[(yc0 * 48 + xc0) * 256 + cb];
      v8s c01v = *(const v8s*)&xb[(yc0 * 48 + xc1) * 256 + cb];
      v8s c10v = *(const v8s*)&xb[(yc1 * 48 + xc0) * 256 + cb];
      v8s c11v = *(const v8s*)&xb[(yc1 * 48 + xc1) * 256 + cb];

      __syncthreads();                        // prev tile's reads complete
      // ---- stage A: 256x64 via global_load_lds, pre-swizzled source
      #pragma unroll
      for (int rd = 0; rd < 4; rd++)
        gload16(wG + (size_t)(rd * 64 + p) * 2304 + t * 256 + c0 + aslot * 8,
                ldsA + rd * 4096 + tid * 8);
      // ---- gather B tile: 64 pos x 64 ch, swizzled ds_write
      unsigned short vb8[8];
      #pragma unroll
      for (int i = 0; i < 8; i++) {
        float v = w00 * bf2f((unsigned short)c00v[i])
                + w01 * bf2f((unsigned short)c01v[i])
                + w10 * bf2f((unsigned short)c10v[i])
                + w11 * bf2f((unsigned short)c11v[i]);
        vb8[i] = f2bf(v);
      }
      *(v8s*)&ldsB[p * 64 + (j ^ (p & 7)) * 8] = *(const v8s*)vb8;
      __syncthreads();                        // drains vmcnt + lgkm

      // ---- MFMA: 16 per wave per K-step
      #pragma unroll
      for (int ki = 0; ki < 2; ki++) {
        v8s af[4], bfr[2];
        #pragma unroll
        for (int fm = 0; fm < 4; fm++) {
          int row = wm * 64 + fm * 16 + r;
          af[fm] = *(const v8s*)&ldsA[row * 64 + (((ki * 4 + q) ^ (r & 7)) * 8)];
        }
        #pragma unroll
        for (int fn = 0; fn < 2; fn++) {
          int row = wn * 32 + fn * 16 + r;
          bfr[fn] = *(const v8s*)&ldsB[row * 64 + (((ki * 4 + q) ^ (r & 7)) * 8)];
        }
        #pragma unroll
        for (int fm = 0; fm < 4; fm++)
          #pragma unroll
          for (int fn = 0; fn < 2; fn++)
            acc[fm][fn] = __builtin_amdgcn_mfma_f32_16x16x32_bf16(af[fm], bfr[fn], acc[fm][fn], 0, 0, 0);
      }
    }
  }

  // ---- epilogue: atomic accumulate (2 exact addends per element)
  float* op = out + (size_t)b * (256 * 2304) + hw0;
  #pragma unroll
  for (int fm = 0; fm < 4; fm++) {
    int co = wm * 64 + fm * 16 + q * 4;
    #pragma unroll
    for (int fn = 0; fn < 2; fn++) {
      int nn = wn * 32 + fn * 16 + r;
      #pragma unroll
      for (int e = 0; e < 4; e++)
        unsafeAtomicAdd(&op[(size_t)(co + e) * 2304 + nn], acc[fm][fn][e]);
    }
  }
}

extern "C" void kernel_launch(void* const* d_in, const int* in_sizes, int n_in,
                              void* d_out, int out_size, void* d_ws, size_t ws_size,
                              hipStream_t stream) {
  const float* x      = (const float*)d_in[0];
  const float* weight = (const float*)d_in[1];
  const float* off_w  = (const float*)d_in[2];
  const float* off_b  = (const float*)d_in[3];
  const float* mask_w = (const float*)d_in[4];
  const float* mask_b = (const float*)d_in[5];
  float* out = (float*)d_out;
  char* ws = (char*)d_ws;

  unsigned short* xT   = (unsigned short*)(ws);             //  9,437,184 B -> 9,437,184
  unsigned short* wG   = (unsigned short*)(ws + 9437184);   //  1,179,648 B -> 10,616,832
  unsigned short* Wc2  = (unsigned short*)(ws + 10616832);  //    147,456 B -> 10,764,288
  unsigned short* zp   = (unsigned short*)(ws + 10764288);  //        512 B -> 10,764,800
  float*          smp  = (float*)(ws + 10764800);           //  1,990,656 B -> 12,755,456
  float*          parS = (float*)(ws + 12755456);           //  7,077,888 B -> 19,833,344

  hipLaunchKernelGGL(k_zero,   dim3(4608),     dim3(256), 0, stream, out);
  hipLaunchKernelGGL(k_wc,     dim3(288),      dim3(256), 0, stream, off_w, mask_w, Wc2, zp);
  hipLaunchKernelGGL(k_wg,     dim3(256),      dim3(256), 0, stream, weight, wG);
  hipLaunchKernelGGL(k_xt,     dim3(1152),     dim3(256), 0, stream, x, xT);
  hipLaunchKernelGGL(k_cg,     dim3(288, 3),   dim3(256), 0, stream, Wc2, xT, zp, parS);
  hipLaunchKernelGGL(k_fin,    dim3(648),      dim3(256), 0, stream, parS, off_b, mask_b, smp);
  hipLaunchKernelGGL(k_fg,     dim3(576),      dim3(512), 0, stream, wG, xT, smp, out);
}

// Round 5
// 114.547 us; speedup vs baseline: 2.1351x; 1.0076x over previous
//
#include <hip/hip_runtime.h>
#include <cstdint>
#include <cmath>

#define DEV __device__ __forceinline__

typedef float v4f __attribute__((ext_vector_type(4)));
typedef short v8s __attribute__((ext_vector_type(8)));

// Problem constants
// x: [8,256,48,48] f32; weight: [256,256,3,3]; off_w: [18,256,3,3]; off_b:[18];
// mask_w: [9,256,3,3]; mask_b:[9]; out: [8,256,48,48] f32
static constexpr int HW    = 48 * 48;        // 2304
static constexpr int NPOS  = 8 * HW;         // 18432

DEV float bf2f(unsigned short u) {
  unsigned int v = ((unsigned int)u) << 16;
  float f; __builtin_memcpy(&f, &v, 4); return f;
}
DEV unsigned short f2bf(float f) {
  unsigned int u; __builtin_memcpy(&u, &f, 4);
  unsigned int r = (u + 0x7fffu + ((u >> 16) & 1u)) >> 16;
  return (unsigned short)r;
}

DEV void gload16(const void* g, void* l) {
  __builtin_amdgcn_global_load_lds(
      (const __attribute__((address_space(1))) unsigned int*)g,
      (__attribute__((address_space(3))) unsigned int*)l, 16, 0, 0);
}

// ---- prep: offset/mask weights -> Wc2[32][k=t*256+c] bf16 (rows 27..31 = 0);
//      also zero the 512B zero-page used for OOB im2col rows.
__global__ void k_wc(const float* __restrict__ off_w, const float* __restrict__ mask_w,
                     unsigned short* __restrict__ Wc2, unsigned short* __restrict__ zp) {
  int i = blockIdx.x * 256 + threadIdx.x;     // 32*2304 = 73728 (288 blocks)
  if (i < 256) zp[i] = 0;
  int o = i / 2304, col = i % 2304;
  int t = col >> 8, c = col & 255;
  float v = 0.f;
  if (o < 18)      v = off_w[(o * 256 + c) * 9 + t];
  else if (o < 27) v = mask_w[((o - 18) * 256 + c) * 9 + t];
  Wc2[i] = f2bf(v);
}

// ---------------- prep: weight OIHW f32 -> wG[co][k*256+c] bf16 --------------
__global__ void k_wg(const float* __restrict__ weight, unsigned short* __restrict__ wG) {
  __shared__ float wrow[2304];
  int co = blockIdx.x;
  const float* wsrc = weight + (size_t)co * 2304;
  for (int i = threadIdx.x; i < 2304; i += 256) wrow[i] = wsrc[i];
  __syncthreads();
  unsigned short* dst = wG + (size_t)co * 2304;
  #pragma unroll
  for (int k = 0; k < 9; k++)
    dst[k * 256 + threadIdx.x] = f2bf(wrow[threadIdx.x * 9 + k]);
}

// ---------------- prep: x NCHW f32 -> xT [b][hw][c] bf16 ---------------------
__global__ void k_xt(const float* __restrict__ x, unsigned short* __restrict__ xT) {
  __shared__ float tile[64][65];
  int bid = blockIdx.x;                 // b*144 + hwt*4 + ct
  int ct = bid & 3; int hwt = (bid >> 2) % 36; int b = bid / 144;
  int c0 = ct * 64, hw0 = hwt * 64;
  int tl = threadIdx.x & 63, tr = threadIdx.x >> 6;
  const float* xb = x + (size_t)(b * 256 + c0) * 2304 + hw0;
  #pragma unroll
  for (int r = 0; r < 16; r++) {
    int cr = tr + r * 4;
    tile[cr][tl] = xb[(size_t)cr * 2304 + tl];
  }
  __syncthreads();
  unsigned short* xo = xT + ((size_t)b * 2304 + hw0) * 256 + c0;
  #pragma unroll
  for (int r = 0; r < 16; r++) {
    int hr = tr + r * 4;
    xo[(size_t)hr * 256 + tl] = f2bf(tile[tl][hr]);
  }
}

// ---------------- offset/mask conv as MFMA GEMM ------------------------------
// S[32][NPOS] = Wc2[32][2304] * im2col(xT)[2304][NPOS], split-K by tap triple.
// grid (288, 3): BN=64, per chunk K=768 (3 taps x 256 ch), BK=64.
// parS layout: [kc][32][NPOS] fp32.
__global__ __launch_bounds__(256) void k_cg(const unsigned short* __restrict__ Wc2,
                                            const unsigned short* __restrict__ xT,
                                            const unsigned short* __restrict__ zp,
                                            float* __restrict__ parS) {
  __shared__ unsigned short ldsA[32 * 64];
  __shared__ unsigned short ldsB[64 * 64];
  int nt = blockIdx.x, kc = blockIdx.y;
  int n0 = nt * 64;
  int b = n0 / 2304, hw0 = n0 % 2304;         // BN=64 divides 2304: one image
  int tid = threadIdx.x, lane = tid & 63, wid = tid >> 6;
  int r = lane & 15, q = lane >> 4;
  int row0 = tid >> 3;                        // staging row (0..31)
  int sslot = (tid & 7) ^ (row0 & 7);         // pre-swizzled 16B slot

  int hwA = hw0 + row0,      hA = hwA / 48, wA = hwA % 48;   // B round 0 row
  int hwB = hw0 + row0 + 32, hB = hwB / 48, wB = hwB % 48;   // B round 1 row

  v4f acc0 = (v4f){0.f, 0.f, 0.f, 0.f};
  v4f acc1 = (v4f){0.f, 0.f, 0.f, 0.f};

  #pragma unroll
  for (int tt = 0; tt < 3; tt++) {
    int t = kc * 3 + tt;
    int dy = kc - 1, dx = tt - 1;
    int yA = hA + dy, xA = wA + dx;
    int yB = hB + dy, xB = wB + dx;
    bool vA = ((unsigned)yA < 48u) && ((unsigned)xA < 48u);
    bool vB = ((unsigned)yB < 48u) && ((unsigned)xB < 48u);
    const unsigned short* baseA2 = Wc2 + (size_t)row0 * 2304 + t * 256 + sslot * 8;
    const unsigned short* base0 = vA ? xT + ((size_t)(b * 2304 + yA * 48 + xA) * 256 + sslot * 8)
                                     : zp + sslot * 8;
    const unsigned short* base1 = vB ? xT + ((size_t)(b * 2304 + yB * 48 + xB) * 256 + sslot * 8)
                                     : zp + sslot * 8;
    #pragma unroll
    for (int cq = 0; cq < 4; cq++) {
      int c0s = cq * 64;
      __syncthreads();                        // prev tile reads done
      gload16(baseA2 + c0s, ldsA + tid * 8);
      gload16(base0  + c0s, ldsB + tid * 8);
      gload16(base1  + c0s, ldsB + 2048 + tid * 8);
      __syncthreads();                        // drain vmcnt + barrier
      #pragma unroll
      for (int ki = 0; ki < 2; ki++) {
        int sl = ((ki * 4 + q) ^ (r & 7)) * 8;
        v8s a0 = *(const v8s*)&ldsA[r * 64 + sl];
        v8s a1 = *(const v8s*)&ldsA[(16 + r) * 64 + sl];
        v8s bb = *(const v8s*)&ldsB[(wid * 16 + r) * 64 + sl];
        acc0 = __builtin_amdgcn_mfma_f32_16x16x32_bf16(a0, bb, acc0, 0, 0, 0);
        acc1 = __builtin_amdgcn_mfma_f32_16x16x32_bf16(a1, bb, acc1, 0, 0, 0);
      }
    }
  }

  float* pp = parS + (size_t)kc * 32 * NPOS + n0;
  #pragma unroll
  for (int e = 0; e < 4; e++) {
    pp[(size_t)(q * 4 + e) * NPOS      + wid * 16 + r] = acc0[e];
    pp[(size_t)(16 + q * 4 + e) * NPOS + wid * 16 + r] = acc1[e];
  }
}

// ---------------- finalize: reduce 3 chunks, bias, sigmoid, coords -----------
// smp layout: [k][pos][{py,px,m}]
__global__ __launch_bounds__(256) void k_fin(const float* __restrict__ parS,
                                             const float* __restrict__ off_b,
                                             const float* __restrict__ mask_b,
                                             float* __restrict__ smp) {
  int k = blockIdx.x / 72;                    // 72 blocks per k (NPOS/256)
  int pos = (blockIdx.x % 72) * 256 + threadIdx.x;
  float s0 = 0.f, s1 = 0.f, s2 = 0.f;
  #pragma unroll
  for (int g = 0; g < 3; g++) {
    const float* pg = parS + (size_t)g * 32 * NPOS + pos;
    s0 += pg[(size_t)(2 * k)     * NPOS];
    s1 += pg[(size_t)(2 * k + 1) * NPOS];
    s2 += pg[(size_t)(18 + k)    * NPOS];
  }
  int hw = pos % 2304; int h = hw / 48, w = hw % 48;
  float m = 1.f / (1.f + expf(-(s2 + mask_b[k])));
  float* sp = smp + ((size_t)k * NPOS + pos) * 3;
  sp[0] = s0 + off_b[2 * k]     + (float)(k / 3) + (float)h - 1.f;
  sp[1] = s1 + off_b[2 * k + 1] + (float)(k % 3) + (float)w - 1.f;
  sp[2] = m;
}

// ---------------- zero the output (required: fused GEMM accumulates) ---------
__global__ __launch_bounds__(256) void k_zero(float* __restrict__ out) {
  int i = blockIdx.x * 256 + threadIdx.x;     // 1179648 float4 = 4608 blocks
  ((v4f*)out)[i] = (v4f){0.f, 0.f, 0.f, 0.f};
}

// ---------------- fused deformable-gather + GEMM (pipelined dbuf) ------------
// C[co][n] += sum_{K-half} wG[co][K] * gather(xT,smp)[K][n]
// BM=256 (full M), BN=64, BK=64. Split-K 2-way by channel-half.
// 576 blocks x 512 threads; XCD-swizzled. 18 K-steps, double-buffered LDS,
// corners+A for step s+1 issued before step s's MFMA; smp prefetched depth-2.
__global__ __launch_bounds__(512, 4) void k_fg(const unsigned short* __restrict__ wG,
                                               const unsigned short* __restrict__ xT,
                                               const float* __restrict__ smp,
                                               float* __restrict__ out) {
  __shared__ unsigned short ldsA[2][256 * 64];   // 2x32 KB, swizzled slots
  __shared__ unsigned short ldsB[2][64 * 64];    // 2x 8 KB, swizzled slots
  int raw = blockIdx.x;                       // 576 = 288 nt x 2 kc
  int vbid = (raw & 7) * 72 + (raw >> 3);     // XCD-contiguous chunks of 72
  int kc = vbid / 288, nt = vbid % 288;
  int n0 = nt * 64;
  int b = n0 / 2304, hw0 = n0 % 2304;         // 64 | 2304: single image
  int tid = threadIdx.x, lane = tid & 63, wid = tid >> 6;
  int wm = wid & 3, wn = wid >> 2;            // 4 m-waves x 2 n-waves
  int r = lane & 15, q = lane >> 4;
  int p = tid >> 3, j = tid & 7;              // gather: 8 threads per position
  int pos = b * 2304 + hw0 + p;
  const unsigned short* xb = xT + (size_t)b * 2304 * 256;
  int aslot = j ^ (p & 7);                    // pre-swizzled A source slot

  v4f acc[4][2];
  #pragma unroll
  for (int i = 0; i < 4; i++)
    #pragma unroll
    for (int jj = 0; jj < 2; jj++) acc[i][jj] = (v4f){0.f, 0.f, 0.f, 0.f};

  float smy, smx, smm;                        // smp for the step we'll issue next
  float w00, w01, w10, w11;                   // weights for in-flight corners
  v8s c00v, c01v, c10v, c11v;                 // in-flight corner data

  // step s: tap t = s % 9, channel base c0 = (kc*2 + s/9)*64
  #define SMPLOAD(s) { const float* sp_ = smp + ((size_t)((s) % 9) * NPOS + pos) * 3; \
                       smy = sp_[0]; smx = sp_[1]; smm = sp_[2]; }
  #define CORNER_ISSUE(s) { \
    float y0f_ = floorf(smy), x0f_ = floorf(smx); \
    float wy_ = smy - y0f_, wx_ = smx - x0f_; \
    int y0_ = (int)y0f_, x0_ = (int)x0f_; \
    bool vy0_ = (y0_ >= 0) && (y0_ <= 47), vy1_ = (y0_ >= -1) && (y0_ <= 46); \
    bool vx0_ = (x0_ >= 0) && (x0_ <= 47), vx1_ = (x0_ >= -1) && (x0_ <= 46); \
    int yc0_ = min(max(y0_, 0), 47), yc1_ = min(max(y0_ + 1, 0), 47); \
    int xc0_ = min(max(x0_, 0), 47), xc1_ = min(max(x0_ + 1, 0), 47); \
    w00 = (1.f - wy_) * (1.f - wx_) * smm * (float)(vy0_ && vx0_); \
    w01 = (1.f - wy_) * wx_         * smm * (float)(vy0_ && vx1_); \
    w10 = wy_         * (1.f - wx_) * smm * (float)(vy1_ && vx0_); \
    w11 = wy_         * wx_         * smm * (float)(vy1_ && vx1_); \
    int cb_ = ((kc * 2 + (s) / 9) * 64) + j * 8; \
    c00v = *(const v8s*)&xb[(yc0_ * 48 + xc0_) * 256 + cb_]; \
    c01v = *(const v8s*)&xb[(yc0_ * 48 + xc1_) * 256 + cb_]; \
    c10v = *(const v8s*)&xb[(yc1_ * 48 + xc0_) * 256 + cb_]; \
    c11v = *(const v8s*)&xb[(yc1_ * 48 + xc1_) * 256 + cb_]; }
  #define A_ISSUE(s, bufi) { int t_ = (s) % 9, c0_ = (kc * 2 + (s) / 9) * 64; \
    _Pragma("unroll") for (int rd_ = 0; rd_ < 4; rd_++) \
      gload16(wG + (size_t)(rd_ * 64 + p) * 2304 + t_ * 256 + c0_ + aslot * 8, \
              &ldsA[bufi][rd_ * 4096 + tid * 8]); }
  #define BWRITE(bufi) { unsigned short vb8_[8]; \
    _Pragma("unroll") for (int i_ = 0; i_ < 8; i_++) { \
      float v_ = w00 * bf2f((unsigned short)c00v[i_]) + w01 * bf2f((unsigned short)c01v[i_]) \
               + w10 * bf2f((unsigned short)c10v[i_]) + w11 * bf2f((unsigned short)c11v[i_]); \
      vb8_[i_] = f2bf(v_); } \
    *(v8s*)&ldsB[bufi][p * 64 + (j ^ (p & 7)) * 8] = *(const v8s*)vb8_; }

  // ---- prologue: fill buffer 0 for step 0; preload smp(1)
  SMPLOAD(0);
  CORNER_ISSUE(0);
  A_ISSUE(0, 0);
  SMPLOAD(1);
  BWRITE(0);
  __syncthreads();

  for (int s = 0; s < 18; s++) {
    int cur = s & 1, nxt = cur ^ 1;
    if (s + 1 < 18) {                         // issue next step's loads early
      CORNER_ISSUE(s + 1);
      A_ISSUE(s + 1, nxt);
    }
    if (s + 2 < 18) SMPLOAD(s + 2);

    __builtin_amdgcn_s_setprio(1);
    #pragma unroll
    for (int ki = 0; ki < 2; ki++) {
      v8s af[4], bfr[2];
      #pragma unroll
      for (int fm = 0; fm < 4; fm++) {
        int row = wm * 64 + fm * 16 + r;
        af[fm] = *(const v8s*)&ldsA[cur][row * 64 + (((ki * 4 + q) ^ (r & 7)) * 8)];
      }
      #pragma unroll
      for (int fn = 0; fn < 2; fn++) {
        int row = wn * 32 + fn * 16 + r;
        bfr[fn] = *(const v8s*)&ldsB[cur][row * 64 + (((ki * 4 + q) ^ (r & 7)) * 8)];
      }
      #pragma unroll
      for (int fm = 0; fm < 4; fm++)
        #pragma unroll
        for (int fn = 0; fn < 2; fn++)
          acc[fm][fn] = __builtin_amdgcn_mfma_f32_16x16x32_bf16(af[fm], bfr[fn], acc[fm][fn], 0, 0, 0);
    }
    __builtin_amdgcn_s_setprio(0);

    if (s + 1 < 18) BWRITE(nxt);              // corners have had the MFMA phase to land
    __syncthreads();                          // one barrier per K-step
  }

  // ---- epilogue: atomic accumulate (2 exact addends per element)
  float* op = out + (size_t)b * (256 * 2304) + hw0;
  #pragma unroll
  for (int fm = 0; fm < 4; fm++) {
    int co = wm * 64 + fm * 16 + q * 4;
    #pragma unroll
    for (int fn = 0; fn < 2; fn++) {
      int nn = wn * 32 + fn * 16 + r;
      #pragma unroll
      for (int e = 0; e < 4; e++)
        unsafeAtomicAdd(&op[(size_t)(co + e) * 2304 + nn], acc[fm][fn][e]);
    }
  }
  #undef SMPLOAD
  #undef CORNER_ISSUE
  #undef A_ISSUE
  #undef BWRITE
}

extern "C" void kernel_launch(void* const* d_in, const int* in_sizes, int n_in,
                              void* d_out, int out_size, void* d_ws, size_t ws_size,
                              hipStream_t stream) {
  const float* x      = (const float*)d_in[0];
  const float* weight = (const float*)d_in[1];
  const float* off_w  = (const float*)d_in[2];
  const float* off_b  = (const float*)d_in[3];
  const float* mask_w = (const float*)d_in[4];
  const float* mask_b = (const float*)d_in[5];
  float* out = (float*)d_out;
  char* ws = (char*)d_ws;

  unsigned short* xT   = (unsigned short*)(ws);             //  9,437,184 B -> 9,437,184
  unsigned short* wG   = (unsigned short*)(ws + 9437184);   //  1,179,648 B -> 10,616,832
  unsigned short* Wc2  = (unsigned short*)(ws + 10616832);  //    147,456 B -> 10,764,288
  unsigned short* zp   = (unsigned short*)(ws + 10764288);  //        512 B -> 10,764,800
  float*          smp  = (float*)(ws + 10764800);           //  1,990,656 B -> 12,755,456
  float*          parS = (float*)(ws + 12755456);           //  7,077,888 B -> 19,833,344

  hipLaunchKernelGGL(k_zero,   dim3(4608),     dim3(256), 0, stream, out);
  hipLaunchKernelGGL(k_wc,     dim3(288),      dim3(256), 0, stream, off_w, mask_w, Wc2, zp);
  hipLaunchKernelGGL(k_wg,     dim3(256),      dim3(256), 0, stream, weight, wG);
  hipLaunchKernelGGL(k_xt,     dim3(1152),     dim3(256), 0, stream, x, xT);
  hipLaunchKernelGGL(k_cg,     dim3(288, 3),   dim3(256), 0, stream, Wc2, xT, zp, parS);
  hipLaunchKernelGGL(k_fin,    dim3(648),      dim3(256), 0, stream, parS, off_b, mask_b, smp);
  hipLaunchKernelGGL(k_fg,     dim3(576),      dim3(512), 0, stream, wG, xT, smp, out);
}